// Round 14
// baseline (568.401 us; speedup 1.0000x reference)
//
#include <hip/hip_runtime.h>
#include <hip/hip_bf16.h>

// Problem constants
#define CIN_   26
#define HIN_   721
#define WIN_   1440
#define K_     9
#define HOUT_  360
#define KH_    9
#define KW_    9
#define COUT_  256
#define WOUT_  720

#define WT     16                 // w-tile per block (720/16 = 45 tiles)
#define CK     (CIN_ * K_)        // 234
#define KPAD   256                // phase-2 K padded (8 k-steps of 32)
#define ACCP   264                // u16 pitch: 528B rows, 16B aligned
#define NMT    (COUT_ / 16)       // 16 m-tiles
#define NKS    (KPAD / 32)        // 8 k-steps
#define NXCD   8
#define HBAND  (HOUT_ / NXCD)     // 45 h-rows per XCD band

typedef short bf16x8 __attribute__((ext_vector_type(8)));
typedef float f32x4  __attribute__((ext_vector_type(4)));

// Fragment-ordered bf16 weight: [(mt*NKS+ks)*64 + lane]*8 + j   (128 KB)
__device__ unsigned short g_whi[NMT * NKS * 64 * 8];
// Per-h psi A-fragments for phase 1: [(h*3 + ks)*64 + lane]*8 + e  (1.1 MB)
__device__ unsigned short g_pfrag[HOUT_ * 3 * 64 * 8];

__device__ __forceinline__ unsigned short f2bf_rne(float f) {
    union { float f; unsigned u; } v; v.f = f;
    unsigned u = v.u;
    unsigned r = (u + 0x7FFFu + ((u >> 16) & 1u)) >> 16;
    return (unsigned short)r;
}

// A-operand layout for mfma_f32_16x16x32_bf16: row m = lane&15, k = ks*32 + (lane>>4)*8 + j
__global__ void prep_weight_kernel(const float* __restrict__ weight) {
    const int bid  = blockIdx.x;        // 0..127  (mt*NKS + ks)
    const int mt   = bid / NKS;
    const int ks   = bid % NKS;
    const int lane = threadIdx.x;       // 0..63
    const int m    = mt * 16 + (lane & 15);
    const int k0   = ks * 32 + (lane >> 4) * 8;
    const int base = ((mt * NKS + ks) * 64 + lane) * 8;
    #pragma unroll
    for (int j = 0; j < 8; ++j) {
        const int k = k0 + j;
        const float w = (k < CK) ? weight[m * CK + k] : 0.f;
        g_whi[base + j] = f2bf_rne(w);
    }
}

// Phase-1 contraction ordering over the 81 (dh,dw) taps, padded to 96:
//   slot s in [0,72):  dh = s>>3, dw = s&7    (adjacent-dw pairs -> float2 loads)
//   slot s in [72,81): dh = s-72, dw = 8      (the dw=8 singles)
//   slot s in [81,96): zero padding
// A-fragment (psi) per h: row m = lane&15 (psi k), slot s = ks*32 + (lane>>4)*8 + e
__global__ void prep_psi_kernel(const float* __restrict__ psi) {
    const int h    = blockIdx.x;        // 0..359
    const int lane = threadIdx.x;       // 0..63
    const int m    = lane & 15;
    const int kg   = lane >> 4;
    #pragma unroll
    for (int ks = 0; ks < 3; ++ks) {
        const int base = ((h * 3 + ks) * 64 + lane) * 8;
        #pragma unroll
        for (int e = 0; e < 8; ++e) {
            const int s = ks * 32 + kg * 8 + e;
            float v = 0.f;
            if (m < 9) {
                if (s < 72)      v = psi[(m * HOUT_ + h) * 81 + (s >> 3) * 9 + (s & 7)];
                else if (s < 81) v = psi[(m * HOUT_ + h) * 81 + (s - 72) * 9 + 8];
            }
            g_pfrag[base + e] = f2bf_rne(v);
        }
    }
}

__global__ __launch_bounds__(256, 8)
void disco_fused_kernel(const float* __restrict__ x,
                        const int*   __restrict__ hi_base,
                        float* __restrict__ out)
{
    __shared__ __align__(16) unsigned short acc_s[WT][ACCP];  // 8448 B only

    const int b    = blockIdx.x;        // 0..16199
    const int xcd  = b & (NXCD - 1);
    const int jb   = b >> 3;            // 0..2024
    const int h    = xcd * HBAND + jb / 45;
    const int tile = jb % 45;
    const int w0   = tile * WT;
    const int tid  = threadIdx.x;

    const int hib = hi_base[h];         // in [0, 716]

    // ---- zero acc_s k-padding cols [234,256) only (race-free vs phase-1 writes) ----
    #pragma unroll
    for (int t = 0; t < 2; ++t) {
        const int e = tid + t * 256;    // 0..511
        if (e < 16 * 22) acc_s[e / 22][234 + e % 22] = 0;
    }

    const int lane = tid & 63;
    const int wid  = tid >> 6;          // 4 waves
    const int n    = lane & 15;
    const int kg   = lane >> 4;

    // ---- load psi A-fragments (precomputed, coalesced 16B/lane) ----
    bf16x8 afrag[3];
    #pragma unroll
    for (int ks = 0; ks < 3; ++ks)
        afrag[ks] = *(const bf16x8*)&g_pfrag[((h * 3 + ks) * 64 + lane) * 8];

    // ---- per-lane wrapped column indices (computed once) ----
    // pair dword t covers cols (2n+2t, 2n+2t+1); both-even base -> never straddles wrap
    const int c0 = 2 * w0 - 4;          // in [-4, 1404], even
    int gp[4];
    #pragma unroll
    for (int t = 0; t < 4; ++t) {
        int g = c0 + 2 * n + 2 * t;
        if (g < 0)          g += WIN_;
        else if (g >= WIN_) g -= WIN_;
        gp[t] = g;
    }
    int gs = c0 + 2 * n + 8;            // singles col (dw=8)
    if (gs < 0)          gs += WIN_;
    else if (gs >= WIN_) gs -= WIN_;

    // ---- phase 1: acc[(c,k)][w] via MFMA, psi as A, x read DIRECT from global ----
    for (int c = wid; c < CIN_; c += 4) {
        const float* xc = x + (size_t)c * (HIN_ * WIN_);
        f32x4 C = {0.f, 0.f, 0.f, 0.f};
        #pragma unroll
        for (int ks = 0; ks < 3; ++ks) {
            union { bf16x8 v; unsigned d[4]; unsigned short u[8]; } bf;
            if (ks < 2 || kg == 0) {
                // pairs: dh = ks*4 + kg (uniform per 16-lane group)
                int r = hib + ks * 4 + kg;
                if (r > HIN_ - 1) r = HIN_ - 1;
                const float* rowp = xc + (size_t)r * WIN_;
                #pragma unroll
                for (int t = 0; t < 4; ++t) {
                    const float2 v = *reinterpret_cast<const float2*>(rowp + gp[t]);
                    const __hip_bfloat162 bv = __float22bfloat162_rn(v);
                    bf.d[t] = *reinterpret_cast<const unsigned*>(&bv);
                }
            } else if (kg == 1) {
                // singles s=72..79: dh = e, dw = 8
                #pragma unroll
                for (int e = 0; e < 8; ++e) {
                    int r = hib + e;
                    if (r > HIN_ - 1) r = HIN_ - 1;
                    bf.u[e] = f2bf_rne(xc[(size_t)r * WIN_ + gs]);
                }
            } else if (kg == 2) {
                bf.d[0] = bf.d[1] = bf.d[2] = bf.d[3] = 0;
                int r = hib + 8;
                if (r > HIN_ - 1) r = HIN_ - 1;
                bf.u[0] = f2bf_rne(xc[(size_t)r * WIN_ + gs]);   // s=80: dh=8, dw=8
            } else {
                bf.d[0] = bf.d[1] = bf.d[2] = bf.d[3] = 0;
            }
            C = __builtin_amdgcn_mfma_f32_16x16x32_bf16(afrag[ks], bf.v, C, 0, 0, 0);
        }
        // C row m = kg*4 + r (psi k), col n = w  ->  acc_s[n][c*9 + m]
        #pragma unroll
        for (int r = 0; r < 4; ++r) {
            const int m = kg * 4 + r;
            if (m < 9) acc_s[n][c * 9 + m] = f2bf_rne(C[r]);
        }
    }
    __syncthreads();

    // ---- phase 2: C[256x16] = W[256xK] * acc[Kx16] via bf16 MFMA ----
    f32x4 C0 = {0.f, 0.f, 0.f, 0.f};
    f32x4 C1 = C0, C2 = C0, C3 = C0;

    for (int ks = 0; ks < NKS; ++ks) {
        const int kof = ks * 32 + kg * 8;             // multiple of 8 -> 16B aligned
        const bf16x8 bhi = *(const bf16x8*)&acc_s[n][kof];

        #pragma unroll
        for (int i = 0; i < 4; ++i) {
            const int mt    = wid * 4 + i;
            const int abase = ((mt * NKS + ks) * 64 + lane) * 8;
            const bf16x8 ahi = *(const bf16x8*)&g_whi[abase];
            f32x4 acc = (i == 0) ? C0 : (i == 1) ? C1 : (i == 2) ? C2 : C3;
            acc = __builtin_amdgcn_mfma_f32_16x16x32_bf16(ahi, bhi, acc, 0, 0, 0);
            if (i == 0) C0 = acc; else if (i == 1) C1 = acc; else if (i == 2) C2 = acc; else C3 = acc;
        }
    }

    // ---- epilogue: D layout col = lane&15, row = (lane>>4)*4 + reg ----
    #pragma unroll
    for (int i = 0; i < 4; ++i) {
        const f32x4 acc = (i == 0) ? C0 : (i == 1) ? C1 : (i == 2) ? C2 : C3;
        const int m0 = (wid * 4 + i) * 16 + kg * 4;
        #pragma unroll
        for (int r = 0; r < 4; ++r) {
            out[(size_t)(m0 + r) * (HOUT_ * WOUT_) + h * WOUT_ + w0 + n] = acc[r];
        }
    }
}

extern "C" void kernel_launch(void* const* d_in, const int* in_sizes, int n_in,
                              void* d_out, int out_size, void* d_ws, size_t ws_size,
                              hipStream_t stream)
{
    const float* x       = (const float*)d_in[0];
    const float* psi     = (const float*)d_in[1];
    const float* weight  = (const float*)d_in[2];
    const int*   hi_base = (const int*)d_in[3];
    float* out = (float*)d_out;

    hipLaunchKernelGGL(prep_weight_kernel, dim3(NMT * NKS), dim3(64), 0, stream, weight);
    hipLaunchKernelGGL(prep_psi_kernel,    dim3(HOUT_),     dim3(64), 0, stream, psi);

    dim3 grid(45 * HOUT_, 1, 1);   // 16200, 1-D for XCD swizzle
    dim3 block(256, 1, 1);
    hipLaunchKernelGGL(disco_fused_kernel, grid, block, 0, stream,
                       x, hi_base, out);
}

// Round 15
// 273.424 us; speedup vs baseline: 2.0788x; 2.0788x over previous
//
#include <hip/hip_runtime.h>
#include <hip/hip_bf16.h>

// Problem constants
#define CIN_   26
#define HIN_   721
#define WIN_   1440
#define K_     9
#define HOUT_  360
#define KH_    9
#define KW_    9
#define COUT_  256
#define WOUT_  720

#define WT     16                 // w-tile per block (720/16 = 45 tiles)
#define XSP    42                 // xs row pitch in u16 (84 B)
#define CK     (CIN_ * K_)        // 234
#define KPAD2  288                // phase-2 K: k' = c*10 + m, 260 -> pad 288 (9 k-steps)
#define NKS2   9
#define ACCP2  296                // u16 pitch: 592 B rows (16B aligned, 2-way banks)
#define NMT    (COUT_ / 16)       // 16 m-tiles
#define NXCD   8
#define HBAND  (HOUT_ / NXCD)     // 45 h-rows per XCD band

typedef short bf16x8 __attribute__((ext_vector_type(8)));
typedef float f32x4  __attribute__((ext_vector_type(4)));

// Fragment-ordered bf16 weight in k'-layout: [(mt*NKS2+ks)*64 + lane]*8 + j  (144 KB)
__device__ unsigned short g_whi[NMT * NKS2 * 64 * 8];
// Per-h psi A-fragments for phase 1: [(h*3 + ks)*64 + lane]*8 + e  (1.1 MB)
__device__ unsigned short g_pfrag[HOUT_ * 3 * 64 * 8];

__device__ __forceinline__ unsigned short f2bf_rne(float f) {
    union { float f; unsigned u; } v; v.f = f;
    unsigned u = v.u;
    unsigned r = (u + 0x7FFFu + ((u >> 16) & 1u)) >> 16;
    return (unsigned short)r;
}
__device__ __forceinline__ unsigned pack_bf2(float a, float b) {
    const __hip_bfloat162 bv = __float22bfloat162_rn(make_float2(a, b));
    return *reinterpret_cast<const unsigned*>(&bv);
}

// A-operand layout for mfma_f32_16x16x32_bf16: row m = lane&15, k = ks*32 + (lane>>4)*8 + j
// k' decoding: c = k'/10, m = k'%10; m==9 or k'>=260 -> zero
__global__ void prep_weight_kernel(const float* __restrict__ weight) {
    const int bid  = blockIdx.x;        // 0..143  (mt*NKS2 + ks)
    const int mt   = bid / NKS2;
    const int ks   = bid % NKS2;
    const int lane = threadIdx.x;       // 0..63
    const int row  = mt * 16 + (lane & 15);
    const int k0   = ks * 32 + (lane >> 4) * 8;
    const int base = ((mt * NKS2 + ks) * 64 + lane) * 8;
    #pragma unroll
    for (int j = 0; j < 8; ++j) {
        const int kp = k0 + j;
        float w = 0.f;
        if (kp < 260) {
            const int c = kp / 10, m = kp % 10;
            if (m < 9) w = weight[row * CK + c * 9 + m];
        }
        g_whi[base + j] = f2bf_rne(w);
    }
}

// Phase-1 contraction ordering over the 81 (dh,dw) taps, padded to 96:
//   slot s in [0,72):  dh = s>>3, dw = s&7    (adjacent-dw pairs)
//   slot s in [72,81): dh = s-72, dw = 8      (the dw=8 singles)
//   slot s in [81,96): zero padding
__global__ void prep_psi_kernel(const float* __restrict__ psi) {
    const int h    = blockIdx.x;        // 0..359
    const int lane = threadIdx.x;       // 0..63
    const int m    = lane & 15;
    const int kg   = lane >> 4;
    #pragma unroll
    for (int ks = 0; ks < 3; ++ks) {
        const int base = ((h * 3 + ks) * 64 + lane) * 8;
        #pragma unroll
        for (int e = 0; e < 8; ++e) {
            const int s = ks * 32 + kg * 8 + e;
            float v = 0.f;
            if (m < 9) {
                if (s < 72)      v = psi[(m * HOUT_ + h) * 81 + (s >> 3) * 9 + (s & 7)];
                else if (s < 81) v = psi[(m * HOUT_ + h) * 81 + (s - 72) * 9 + 8];
            }
            g_pfrag[base + e] = f2bf_rne(v);
        }
    }
}

__global__ __launch_bounds__(256, 5)
void disco_fused_kernel(const float* __restrict__ x,
                        const int*   __restrict__ hi_base,
                        float* __restrict__ out)
{
    __shared__ unsigned short xs_bf[CK][XSP];                  // 19656 B
    __shared__ __align__(16) unsigned short acc_s[WT][ACCP2];  //  9472 B  (29128 total -> 5/CU)

    const int b    = blockIdx.x;        // 0..16199
    const int xcd  = b & (NXCD - 1);
    const int jb   = b >> 3;            // 0..2024
    const int h    = xcd * HBAND + jb / 45;
    const int tile = jb % 45;
    const int w0   = tile * WT;
    const int tid  = threadIdx.x;

    const int hib = hi_base[h];         // in [0, 716]

    // ---- zero acc_s k'-padding cols [260,288) ----
    #pragma unroll
    for (int t = 0; t < 2; ++t) {
        const int e = tid + t * 256;    // 0..511
        if (e < 16 * 28) acc_s[e / 28][260 + e % 28] = 0;
    }

    // ---- stage x tile as bf16 pairs, coalesced: i -> (row = i/20, pair p = i%20) ----
    // pair p covers cols (2p, 2p+1); base even -> never straddles the mod-1440 wrap
    const int c0 = 2 * w0 - 4;          // in [-4, 1404], even
    for (int i = tid; i < CK * 20; i += 256) {
        const int p   = i % 20;
        const int row = i / 20;         // c*9 + dh
        const int dh  = row % KH_;
        const int c   = row / KH_;
        int r = hib + dh;
        if (r > HIN_ - 1) r = HIN_ - 1;
        int g = c0 + 2 * p;
        if (g < 0)          g += WIN_;
        else if (g >= WIN_) g -= WIN_;
        const float2 v = *reinterpret_cast<const float2*>(x + ((size_t)c * HIN_ + r) * WIN_ + g);
        *reinterpret_cast<unsigned*>(&xs_bf[row][2 * p]) = pack_bf2(v.x, v.y);
    }

    const int lane = tid & 63;
    const int wid  = tid >> 6;          // 4 waves
    const int n    = lane & 15;
    const int kg   = lane >> 4;

    // ---- load psi A-fragments (precomputed, coalesced 16B/lane) ----
    bf16x8 afrag[3];
    #pragma unroll
    for (int ks = 0; ks < 3; ++ks)
        afrag[ks] = *(const bf16x8*)&g_pfrag[((h * 3 + ks) * 64 + lane) * 8];

    __syncthreads();

    // ---- phase 1: acc[(c,m)][w] via MFMA, psi as A, xs as B; packed writeback ----
    const char* xsb = (const char*)&xs_bf[0][0];
    for (int c = wid; c < CIN_; c += 4) {
        const int base = c * (KH_ * XSP * 2) + 4 * n;   // byte offset: c*756 + 4n
        f32x4 C = {0.f, 0.f, 0.f, 0.f};
        #pragma unroll
        for (int ks = 0; ks < 3; ++ks) {
            union { bf16x8 v; unsigned d[4]; unsigned short u[8]; } bf;
            if (ks < 2 || kg == 0) {
                // pairs: dh = ks*4 + kg (uniform per 16-lane group)
                const char* p = xsb + base + (ks * 4 + kg) * (XSP * 2);
                #pragma unroll
                for (int t = 0; t < 4; ++t)
                    bf.d[t] = *(const unsigned*)(p + 4 * t);
            } else if (kg == 1) {
                // singles s=72..79: dh = e, dw = 8 -> byte = e*84 + 4n + 16
                #pragma unroll
                for (int e = 0; e < 8; ++e)
                    bf.u[e] = *(const unsigned short*)(xsb + base + e * (XSP * 2) + 16);
            } else if (kg == 2) {
                bf.d[0] = bf.d[1] = bf.d[2] = bf.d[3] = 0;
                bf.u[0] = *(const unsigned short*)(xsb + base + 8 * (XSP * 2) + 16);  // s=80
            } else {
                bf.d[0] = bf.d[1] = bf.d[2] = bf.d[3] = 0;
            }
            C = __builtin_amdgcn_mfma_f32_16x16x32_bf16(afrag[ks], bf.v, C, 0, 0, 0);
        }
        // C row m = kg*4 + r -> acc_s[n][c*10 + m], packed pair stores (4B aligned)
        if (kg < 2) {
            unsigned* ap = reinterpret_cast<unsigned*>(&acc_s[n][c * 10 + kg * 4]);
            ap[0] = pack_bf2(C[0], C[1]);
            ap[1] = pack_bf2(C[2], C[3]);
        } else if (kg == 2) {
            *reinterpret_cast<unsigned*>(&acc_s[n][c * 10 + 8]) = pack_bf2(C[0], 0.f);
        }
    }
    __syncthreads();

    // ---- phase 2: C[256x16] = W[256xK'] * acc[K'x16] via bf16 MFMA, 9 k-steps ----
    f32x4 C0 = {0.f, 0.f, 0.f, 0.f};
    f32x4 C1 = C0, C2 = C0, C3 = C0;

    for (int ks = 0; ks < NKS2; ++ks) {
        const int kof = ks * 32 + kg * 8;             // multiple of 8 -> 16B aligned
        const bf16x8 bhi = *(const bf16x8*)&acc_s[n][kof];

        #pragma unroll
        for (int i = 0; i < 4; ++i) {
            const int mt    = wid * 4 + i;
            const int abase = ((mt * NKS2 + ks) * 64 + lane) * 8;
            const bf16x8 ahi = *(const bf16x8*)&g_whi[abase];
            f32x4 acc = (i == 0) ? C0 : (i == 1) ? C1 : (i == 2) ? C2 : C3;
            acc = __builtin_amdgcn_mfma_f32_16x16x32_bf16(ahi, bhi, acc, 0, 0, 0);
            if (i == 0) C0 = acc; else if (i == 1) C1 = acc; else if (i == 2) C2 = acc; else C3 = acc;
        }
    }

    // ---- epilogue: D layout col = lane&15, row = (lane>>4)*4 + reg ----
    #pragma unroll
    for (int i = 0; i < 4; ++i) {
        const f32x4 acc = (i == 0) ? C0 : (i == 1) ? C1 : (i == 2) ? C2 : C3;
        const int m0 = (wid * 4 + i) * 16 + kg * 4;
        #pragma unroll
        for (int r = 0; r < 4; ++r) {
            out[(size_t)(m0 + r) * (HOUT_ * WOUT_) + h * WOUT_ + w0 + n] = acc[r];
        }
    }
}

extern "C" void kernel_launch(void* const* d_in, const int* in_sizes, int n_in,
                              void* d_out, int out_size, void* d_ws, size_t ws_size,
                              hipStream_t stream)
{
    const float* x       = (const float*)d_in[0];
    const float* psi     = (const float*)d_in[1];
    const float* weight  = (const float*)d_in[2];
    const int*   hi_base = (const int*)d_in[3];
    float* out = (float*)d_out;

    hipLaunchKernelGGL(prep_weight_kernel, dim3(NMT * NKS2), dim3(64), 0, stream, weight);
    hipLaunchKernelGGL(prep_psi_kernel,    dim3(HOUT_),      dim3(64), 0, stream, psi);

    dim3 grid(45 * HOUT_, 1, 1);   // 16200, 1-D for XCD swizzle
    dim3 block(256, 1, 1);
    hipLaunchKernelGGL(disco_fused_kernel, grid, block, 0, stream,
                       x, hi_base, out);
}

// Round 16
// 265.812 us; speedup vs baseline: 2.1384x; 1.0286x over previous
//
#include <hip/hip_runtime.h>
#include <hip/hip_bf16.h>

// Problem constants
#define CIN_   26
#define HIN_   721
#define WIN_   1440
#define K_     9
#define HOUT_  360
#define KH_    9
#define KW_    9
#define COUT_  256
#define WOUT_  720

#define WT     16                 // w-tile per block (720/16 = 45 tiles)
#define XSP    42                 // xs row pitch in u16 (84 B)
#define CK     (CIN_ * K_)        // 234
#define KPAD2  288                // phase-2 K: k' = c*10 + m, 260 -> pad 288 (9 k-steps)
#define NKS2   9
#define ACCP2  296                // u16 pitch: 592 B rows (16B aligned, 2-way banks)
#define NMT    (COUT_ / 16)       // 16 m-tiles
#define NXCD   8
#define HBAND  (HOUT_ / NXCD)     // 45 h-rows per XCD band
#define NSTG   19                 // ceil(CK*20 / 256)

typedef short bf16x8 __attribute__((ext_vector_type(8)));
typedef float f32x4  __attribute__((ext_vector_type(4)));

// Fragment-ordered bf16 weight in k'-layout: [(mt*NKS2+ks)*64 + lane]*8 + j  (144 KB)
__device__ unsigned short g_whi[NMT * NKS2 * 64 * 8];
// Per-h psi A-fragments for phase 1: [(h*3 + ks)*64 + lane]*8 + e  (1.1 MB)
__device__ unsigned short g_pfrag[HOUT_ * 3 * 64 * 8];

__device__ __forceinline__ unsigned short f2bf_rne(float f) {
    union { float f; unsigned u; } v; v.f = f;
    unsigned u = v.u;
    unsigned r = (u + 0x7FFFu + ((u >> 16) & 1u)) >> 16;
    return (unsigned short)r;
}
__device__ __forceinline__ unsigned pack_bf2(float a, float b) {
    const __hip_bfloat162 bv = __float22bfloat162_rn(make_float2(a, b));
    return *reinterpret_cast<const unsigned*>(&bv);
}

// A-operand layout for mfma_f32_16x16x32_bf16: row m = lane&15, k = ks*32 + (lane>>4)*8 + j
// k' decoding: c = k'/10, m = k'%10; m==9 or k'>=260 -> zero
__global__ void prep_weight_kernel(const float* __restrict__ weight) {
    const int bid  = blockIdx.x;        // 0..143  (mt*NKS2 + ks)
    const int mt   = bid / NKS2;
    const int ks   = bid % NKS2;
    const int lane = threadIdx.x;       // 0..63
    const int row  = mt * 16 + (lane & 15);
    const int k0   = ks * 32 + (lane >> 4) * 8;
    const int base = ((mt * NKS2 + ks) * 64 + lane) * 8;
    #pragma unroll
    for (int j = 0; j < 8; ++j) {
        const int kp = k0 + j;
        float w = 0.f;
        if (kp < 260) {
            const int c = kp / 10, m = kp % 10;
            if (m < 9) w = weight[row * CK + c * 9 + m];
        }
        g_whi[base + j] = f2bf_rne(w);
    }
}

// Phase-1 contraction ordering over the 81 (dh,dw) taps, padded to 96:
//   slot s in [0,72):  dh = s>>3, dw = s&7    (adjacent-dw pairs)
//   slot s in [72,81): dh = s-72, dw = 8      (the dw=8 singles)
//   slot s in [81,96): zero padding
__global__ void prep_psi_kernel(const float* __restrict__ psi) {
    const int h    = blockIdx.x;        // 0..359
    const int lane = threadIdx.x;       // 0..63
    const int m    = lane & 15;
    const int kg   = lane >> 4;
    #pragma unroll
    for (int ks = 0; ks < 3; ++ks) {
        const int base = ((h * 3 + ks) * 64 + lane) * 8;
        #pragma unroll
        for (int e = 0; e < 8; ++e) {
            const int s = ks * 32 + kg * 8 + e;
            float v = 0.f;
            if (m < 9) {
                if (s < 72)      v = psi[(m * HOUT_ + h) * 81 + (s >> 3) * 9 + (s & 7)];
                else if (s < 81) v = psi[(m * HOUT_ + h) * 81 + (s - 72) * 9 + 8];
            }
            g_pfrag[base + e] = f2bf_rne(v);
        }
    }
}

__global__ __launch_bounds__(256, 4)
void disco_fused_kernel(const float* __restrict__ x,
                        const int*   __restrict__ hi_base,
                        float* __restrict__ out)
{
    __shared__ unsigned short xs_bf[CK][XSP];                  // 19656 B
    __shared__ __align__(16) unsigned short acc_s[WT][ACCP2];  //  9472 B  (29128 total)

    const int b    = blockIdx.x;        // 0..16199
    const int xcd  = b & (NXCD - 1);
    const int jb   = b >> 3;            // 0..2024
    const int h    = xcd * HBAND + jb / 45;
    const int tile = jb % 45;
    const int w0   = tile * WT;
    const int tid  = threadIdx.x;

    const int hib = hi_base[h];         // in [0, 716]

    // ---- zero acc_s k'-padding cols [260,288) ----
    #pragma unroll
    for (int t = 0; t < 2; ++t) {
        const int e = tid + t * 256;    // 0..511
        if (e < 16 * 28) acc_s[e / 28][260 + e % 28] = 0;
    }

    // ---- stage x tile as bf16 pairs, T14 split: issue ALL loads first ----
    // i -> (row = i/20, pair p = i%20); pair covers cols (2p,2p+1); c0 even ->
    // pairs never straddle the mod-1440 wrap.
    const int c0 = 2 * w0 - 4;          // in [-4, 1404], even
    float2 sv[NSTG];
    int    soff[NSTG];
    #pragma unroll
    for (int t = 0; t < NSTG; ++t) {
        const int i = tid + t * 256;
        const bool valid = (i < CK * 20);
        const int ii  = valid ? i : 0;
        const int p   = ii % 20;
        const int row = ii / 20;        // c*9 + dh
        const int dh  = row % KH_;
        const int c   = row / KH_;
        int r = hib + dh;
        if (r > HIN_ - 1) r = HIN_ - 1;
        int g = c0 + 2 * p;
        if (g < 0)          g += WIN_;
        else if (g >= WIN_) g -= WIN_;
        sv[t]   = *reinterpret_cast<const float2*>(x + ((size_t)c * HIN_ + r) * WIN_ + g);
        soff[t] = valid ? (row * XSP + 2 * p) : -1;
    }
    #pragma unroll
    for (int t = 0; t < NSTG; ++t) {
        if (soff[t] >= 0)
            *reinterpret_cast<unsigned*>(&xs_bf[0][0] + soff[t]) = pack_bf2(sv[t].x, sv[t].y);
    }

    const int lane = tid & 63;
    const int wid  = tid >> 6;          // 4 waves
    const int n    = lane & 15;
    const int kg   = lane >> 4;

    // ---- load psi A-fragments (precomputed, coalesced 16B/lane) ----
    bf16x8 afrag[3];
    #pragma unroll
    for (int ks = 0; ks < 3; ++ks)
        afrag[ks] = *(const bf16x8*)&g_pfrag[((h * 3 + ks) * 64 + lane) * 8];

    __syncthreads();

    // ---- phase 1: acc[(c,m)][w] via MFMA, psi as A, xs as B; packed writeback ----
    const char* xsb = (const char*)&xs_bf[0][0];
    for (int c = wid; c < CIN_; c += 4) {
        const int base = c * (KH_ * XSP * 2) + 4 * n;   // byte offset: c*756 + 4n
        f32x4 C = {0.f, 0.f, 0.f, 0.f};
        #pragma unroll
        for (int ks = 0; ks < 3; ++ks) {
            union { bf16x8 v; unsigned d[4]; unsigned short u[8]; } bf;
            if (ks < 2 || kg == 0) {
                // pairs: dh = ks*4 + kg (uniform per 16-lane group)
                const char* p = xsb + base + (ks * 4 + kg) * (XSP * 2);
                #pragma unroll
                for (int t = 0; t < 4; ++t)
                    bf.d[t] = *(const unsigned*)(p + 4 * t);
            } else if (kg == 1) {
                // singles s=72..79: dh = e, dw = 8 -> byte = e*84 + 4n + 16
                #pragma unroll
                for (int e = 0; e < 8; ++e)
                    bf.u[e] = *(const unsigned short*)(xsb + base + e * (XSP * 2) + 16);
            } else if (kg == 2) {
                bf.d[0] = bf.d[1] = bf.d[2] = bf.d[3] = 0;
                bf.u[0] = *(const unsigned short*)(xsb + base + 8 * (XSP * 2) + 16);  // s=80
            } else {
                bf.d[0] = bf.d[1] = bf.d[2] = bf.d[3] = 0;
            }
            C = __builtin_amdgcn_mfma_f32_16x16x32_bf16(afrag[ks], bf.v, C, 0, 0, 0);
        }
        // C row m = kg*4 + r -> acc_s[n][c*10 + m], packed pair stores (4B aligned)
        if (kg < 2) {
            unsigned* ap = reinterpret_cast<unsigned*>(&acc_s[n][c * 10 + kg * 4]);
            ap[0] = pack_bf2(C[0], C[1]);
            ap[1] = pack_bf2(C[2], C[3]);
        } else if (kg == 2) {
            *reinterpret_cast<unsigned*>(&acc_s[n][c * 10 + 8]) = pack_bf2(C[0], 0.f);
        }
    }
    __syncthreads();

    // ---- phase 2: C[256x16] = W[256xK'] * acc[K'x16], weight software-pipelined ----
    f32x4 C0 = {0.f, 0.f, 0.f, 0.f};
    f32x4 C1 = C0, C2 = C0, C3 = C0;

    // frag(i, ks) at wp + (i*NKS2 + ks)*512   (u16 units; 512 = 64 lanes * 8)
    const unsigned short* wp = g_whi + ((size_t)(wid * 4) * NKS2 * 64 + lane) * 8;

    bf16x8 wc[4];
    #pragma unroll
    for (int i = 0; i < 4; ++i)
        wc[i] = *(const bf16x8*)(wp + (size_t)i * NKS2 * 512);

    #pragma unroll
    for (int ks = 0; ks < NKS2; ++ks) {
        bf16x8 wn[4];
        if (ks + 1 < NKS2) {
            #pragma unroll
            for (int i = 0; i < 4; ++i)
                wn[i] = *(const bf16x8*)(wp + ((size_t)i * NKS2 + (ks + 1)) * 512);
        }
        const bf16x8 bhi = *(const bf16x8*)&acc_s[n][ks * 32 + kg * 8];
        C0 = __builtin_amdgcn_mfma_f32_16x16x32_bf16(wc[0], bhi, C0, 0, 0, 0);
        C1 = __builtin_amdgcn_mfma_f32_16x16x32_bf16(wc[1], bhi, C1, 0, 0, 0);
        C2 = __builtin_amdgcn_mfma_f32_16x16x32_bf16(wc[2], bhi, C2, 0, 0, 0);
        C3 = __builtin_amdgcn_mfma_f32_16x16x32_bf16(wc[3], bhi, C3, 0, 0, 0);
        if (ks + 1 < NKS2) {
            #pragma unroll
            for (int i = 0; i < 4; ++i) wc[i] = wn[i];
        }
    }

    // ---- epilogue: D layout col = lane&15, row = (lane>>4)*4 + reg ----
    #pragma unroll
    for (int i = 0; i < 4; ++i) {
        const f32x4 acc = (i == 0) ? C0 : (i == 1) ? C1 : (i == 2) ? C2 : C3;
        const int m0 = (wid * 4 + i) * 16 + kg * 4;
        #pragma unroll
        for (int r = 0; r < 4; ++r) {
            out[(size_t)(m0 + r) * (HOUT_ * WOUT_) + h * WOUT_ + w0 + n] = acc[r];
        }
    }
}

extern "C" void kernel_launch(void* const* d_in, const int* in_sizes, int n_in,
                              void* d_out, int out_size, void* d_ws, size_t ws_size,
                              hipStream_t stream)
{
    const float* x       = (const float*)d_in[0];
    const float* psi     = (const float*)d_in[1];
    const float* weight  = (const float*)d_in[2];
    const int*   hi_base = (const int*)d_in[3];
    float* out = (float*)d_out;

    hipLaunchKernelGGL(prep_weight_kernel, dim3(NMT * NKS2), dim3(64), 0, stream, weight);
    hipLaunchKernelGGL(prep_psi_kernel,    dim3(HOUT_),      dim3(64), 0, stream, psi);

    dim3 grid(45 * HOUT_, 1, 1);   // 16200, 1-D for XCD swizzle
    dim3 block(256, 1, 1);
    hipLaunchKernelGGL(disco_fused_kernel, grid, block, 0, stream,
                       x, hi_base, out);
}